// Round 1
// 137.576 us; speedup vs baseline: 1.0779x; 1.0779x over previous
//
#include <hip/hip_runtime.h>

// Problem: NormalizedHistogram — x:[32,512,512,3] f32 in [0,1] -> [32,256,3] f32
// Per-(image,channel) 256-bin histogram, normalized by its sum.
// Sum is always H*W = 262144 = 2^18, so normalization is an exact *2^-18 scale.
//
// V2: atomic-free epilogue. Each block stores its 768 u32 counts (already in
// out-layout bin*3+c) as a coalesced 3 KB partial into d_ws; a 96-block reduce
// kernel sums the 64 partials per output element (u32, exact) and writes
// count * 2^-18 (exact, count < 2^24). Removes 1.57M device-scope float
// atomics + the zero_kernel. Deterministic, absmax 0.

#define NBINS      256
#define B_IMG      32
#define HW         (512 * 512)          // 262144 pixels per image
#define CH         3
#define ELEM_IMG   (HW * CH)            // 786432 floats per image
#define F4_IMG     (ELEM_IMG / 4)       // 196608 float4 per image
#define THREADS    256
#define BLK_IMG    64                   // blocks per image (2048 total)
#define THR_IMG    (THREADS * BLK_IMG)  // 16384 threads per image
#define F4_THR     (F4_IMG / THR_IMG)   // 12 float4 per thread
#define PJ         (CH * NBINS)         // 768 counters per block
#define NPART      (B_IMG * BLK_IMG)    // 2048 partial histograms
#define OUT_ELEMS  (B_IMG * NBINS * CH) // 24576
#define PART_BYTES ((size_t)NPART * PJ * sizeof(unsigned int)) // 6 MB

typedef float floatx4 __attribute__((ext_vector_type(4)));

__global__ __launch_bounds__(THREADS) void zero_kernel(float* __restrict__ out) {
    int i = blockIdx.x * THREADS + threadIdx.x;
    if (i < OUT_ELEMS) out[i] = 0.0f;
}

template <bool USE_PART>
__global__ __launch_bounds__(THREADS) void hist_kernel(const floatx4* __restrict__ x,
                                                       unsigned int* __restrict__ part,
                                                       float* __restrict__ out) {
    __shared__ unsigned int hist[PJ]; // [c][bin], 3 KB

    const int tid = threadIdx.x;
    hist[tid] = 0u; hist[tid + 256] = 0u; hist[tid + 512] = 0u;
    __syncthreads();

    const int b = blockIdx.y;
    const floatx4* __restrict__ xb = x + (size_t)b * F4_IMG;
    const int t = blockIdx.x * THREADS + tid; // 0..THR_IMG-1

    // channel of element 4*f: (4t + i*65536) % 3 = (t + i) % 3  (strength-reduced)
    int c0 = t % 3;

#pragma unroll
    for (int i = 0; i < F4_THR; ++i) {
        const floatx4 v = __builtin_nontemporal_load(&xb[t + i * THR_IMG]);
        const int cB = (c0 == 2) ? 0 : c0 + 1;
        const int cC = (cB == 2) ? 0 : cB + 1;

        int b0 = min(NBINS - 1, max(0, (int)(v.x * 256.0f)));
        atomicAdd(&hist[(c0 << 8) + b0], 1u);
        int b1 = min(NBINS - 1, max(0, (int)(v.y * 256.0f)));
        atomicAdd(&hist[(cB << 8) + b1], 1u);
        int b2 = min(NBINS - 1, max(0, (int)(v.z * 256.0f)));
        atomicAdd(&hist[(cC << 8) + b2], 1u);
        int b3 = min(NBINS - 1, max(0, (int)(v.w * 256.0f)));
        atomicAdd(&hist[(c0 << 8) + b3], 1u); // .w has same channel as .x

        c0 = cB;
    }

    __syncthreads();

    if (USE_PART) {
        // Coalesced 3 KB store of partial counts, permuted into out-layout
        // jo = bin*CH + c  (so the reduce kernel is fully coalesced load+store).
        unsigned int* __restrict__ pb =
            part + (size_t)(b * BLK_IMG + blockIdx.x) * PJ;
#pragma unroll
        for (int s = 0; s < 3; ++s) {
            const int jo  = tid + s * THREADS;
            const int c   = jo % 3;
            const int bin = jo / 3;
            pb[jo] = hist[(c << 8) + bin];
        }
    } else {
        // Fallback: legacy atomic flush (requires zero_kernel first).
        float* __restrict__ ob = out + (size_t)b * PJ;
        for (int j = tid; j < PJ; j += THREADS) {
            unsigned int cnt = hist[j];
            if (cnt) {
                int c = j >> 8, bin = j & 255;
                atomicAdd(&ob[bin * CH + c], (float)cnt * (1.0f / (float)HW));
            }
        }
    }
}

__global__ __launch_bounds__(THREADS) void reduce_kernel(const unsigned int* __restrict__ part,
                                                         float* __restrict__ out) {
    const int t  = blockIdx.x * THREADS + threadIdx.x; // 0..24575, wave-aligned per image
    const int b  = t / PJ;
    const int jo = t - b * PJ;
    const unsigned int* __restrict__ pb = part + (size_t)b * BLK_IMG * PJ + jo;

    unsigned int s0 = 0, s1 = 0, s2 = 0, s3 = 0;
#pragma unroll 8
    for (int k = 0; k < BLK_IMG; k += 4) {
        s0 += pb[(size_t)(k + 0) * PJ];
        s1 += pb[(size_t)(k + 1) * PJ];
        s2 += pb[(size_t)(k + 2) * PJ];
        s3 += pb[(size_t)(k + 3) * PJ];
    }
    // count * 2^-18 is exact (count < 2^24), deterministic.
    out[t] = (float)(s0 + s1 + s2 + s3) * (1.0f / (float)HW);
}

extern "C" void kernel_launch(void* const* d_in, const int* in_sizes, int n_in,
                              void* d_out, int out_size, void* d_ws, size_t ws_size,
                              hipStream_t stream) {
    const floatx4* x = (const floatx4*)d_in[0];
    float* out = (float*)d_out;

    dim3 grid(BLK_IMG, B_IMG); // 64 x 32 = 2048 blocks

    if (ws_size >= PART_BYTES) {
        unsigned int* part = (unsigned int*)d_ws;
        hist_kernel<true><<<grid, THREADS, 0, stream>>>(x, part, out);
        reduce_kernel<<<OUT_ELEMS / THREADS, THREADS, 0, stream>>>(part, out);
    } else {
        zero_kernel<<<(OUT_ELEMS + THREADS - 1) / THREADS, THREADS, 0, stream>>>(out);
        hist_kernel<false><<<grid, THREADS, 0, stream>>>(x, nullptr, out);
    }
}